// Round 2
// baseline (690.477 us; speedup 1.0000x reference)
//
#include <hip/hip_runtime.h>

// ReactantStage2: N=250000 nodes, D=256 f32, B=8192 graphs, batch sorted asc.
// out[i] = [ node_rep[i] (256 f32),
//            gate(batch[i]) ? mean(label==-1 rows of graph batch[i]) : 0 (256 f32) ]
//
// DTYPE (R1 post-mortem): all float tensors are FLOAT32 on device (reference
// declares jnp.float32; observed absmax 5.617 matches the misplaced-f32 raw-copy
// signature of the bf16 misread, and is inconsistent with a correct bf16 kernel).
// batch / primary_label are int32; num_graphs is a 1-elem int array.

// ---------------- Kernel 1: per-graph condition-mean pool -------------------
// One wave (64 lanes) per graph; lane owns 4 consecutive f32 columns (16 B).
__global__ __launch_bounds__(256) void pool_kernel(
    const float* __restrict__ node_rep,   // [N,256] f32
    const int*   __restrict__ batch,      // [N] int32, sorted
    const int*   __restrict__ label,      // [N] int32
    const int*   __restrict__ num_graphs, // [1]
    float*       __restrict__ pool,       // [B,256] f32 (workspace, 8 MB)
    int n)
{
    const int g    = (blockIdx.x * blockDim.x + threadIdx.x) >> 6;
    const int lane = threadIdx.x & 63;
    const int B    = num_graphs[0];
    if (g >= B) return;

    // lower_bound(g) and lower_bound(g+1) over sorted batch[]
    int lo = 0, hi = n;
    while (lo < hi) { int mid = (lo + hi) >> 1; if (batch[mid] < g) lo = mid + 1; else hi = mid; }
    const int start = lo;
    hi = n;                               // lo already >= start
    while (lo < hi) { int mid = (lo + hi) >> 1; if (batch[mid] < g + 1) lo = mid + 1; else hi = mid; }
    const int end = lo;

    const int col = lane << 2;            // 4 f32 columns per lane
    float ax = 0.f, ay = 0.f, az = 0.f, aw = 0.f;
    int cnt = 0;
    for (int i = start; i < end; ++i) {
        if (label[i] == -1) {             // wave-uniform branch (broadcast load)
            const float4 v = *reinterpret_cast<const float4*>(
                node_rep + (size_t)i * 256 + col);
            ax += v.x; ay += v.y; az += v.z; aw += v.w;
            ++cnt;
        }
    }
    // gate: graph non-empty AND last node of the graph has label -1
    const bool gate = (end > start) && (label[end - 1] == -1);
    const float inv = gate ? 1.0f / (float)(cnt > 0 ? cnt : 1) : 0.0f;
    float4 o;
    o.x = ax * inv; o.y = ay * inv; o.z = az * inv; o.w = aw * inv;
    *reinterpret_cast<float4*>(pool + (size_t)g * 256 + col) = o;
}

// ---------------- Kernel 2: concat + broadcast gather -----------------------
// One thread per 16 B chunk. Output row = 2048 B = 128 chunks; node row and
// pool row = 1024 B = 64 chunks each. Each 64-lane wave lies entirely inside
// one half of one row, so batch[row] is wave-uniform and both halves coalesce.
__global__ __launch_bounds__(256) void concat_kernel(
    const uint4* __restrict__ node4,  // [N,64]  (16 B chunks)
    const int*   __restrict__ batch,  // [N]
    const uint4* __restrict__ pool4,  // [B,64]
    uint4*       __restrict__ out4,   // [N,128]
    int n)
{
    const int idx = blockIdx.x * blockDim.x + threadIdx.x;
    const int row = idx >> 7;
    const int c   = idx & 127;
    if (row >= n) return;
    uint4 v;
    if (c < 64) {
        v = node4[(size_t)row * 64 + c];
    } else {
        const int b = batch[row];         // wave-uniform broadcast load
        v = pool4[(size_t)b * 64 + (c - 64)];
    }
    out4[(size_t)row * 128 + c] = v;
}

extern "C" void kernel_launch(void* const* d_in, const int* in_sizes, int n_in,
                              void* d_out, int out_size, void* d_ws, size_t ws_size,
                              hipStream_t stream) {
    const float* node_rep = (const float*)d_in[0];
    const int*   batch    = (const int*)d_in[1];
    const int*   label    = (const int*)d_in[2];
    const int*   num_g    = (const int*)d_in[3];
    const int    n        = in_sizes[1];          // 250000
    const int    B_max    = 8192;                 // fixed by problem setup

    float* pool = (float*)d_ws;                   // [8192,256] f32 = 8 MB

    // Kernel 1: one wave per graph, 4 waves/block -> 2048 blocks
    {
        const int blocks = (B_max * 64 + 255) / 256;
        hipLaunchKernelGGL(pool_kernel, dim3(blocks), dim3(256), 0, stream,
                           node_rep, batch, label, num_g, pool, n);
    }
    // Kernel 2: one thread per 16 B output chunk -> N*128 threads
    {
        const long long threads = (long long)n * 128;
        const int blocks = (int)((threads + 255) / 256);
        hipLaunchKernelGGL(concat_kernel, dim3(blocks), dim3(256), 0, stream,
                           (const uint4*)node_rep, batch, (const uint4*)pool,
                           (uint4*)d_out, n);
    }
}